// Round 4
// baseline (515.642 us; speedup 1.0000x reference)
//
#include <hip/hip_runtime.h>

// Problem: B=32, C=2048, Q=128, E=200. Inputs fp32, OUTPUT fp32 (B,C,4E).
// R2 post-mortem: XCD swizzle + LDS aliasing in row2 REGRESSED; reverted.
// R3 post-mortem: tail is launch/fixed overhead (~25-30us x n_kernels), not
//   kernel time. R4: 6->4 kernels; row2 TB 32->16 (LDS 42.5->20.9 KB,
//   3->7 blocks/CU) keeping the exact 2-barrier structure.
#define B_ 32
#define C_ 2048
#define Q_ 128
#define E_ 200
#define TB 16    // c-rows per block in row2_kernel

typedef __attribute__((ext_vector_type(4))) float f32x4;

// ---------------------------------------------------------------- K0: prep
// blocks 0..895:    xqT[b][e][q] = xq[b][q][e] via padded-LDS 32x32 tile
// blocks 896..1919: s_q[b,q] = dot(xq[b,q,:], w2), one wave per q-row
__global__ __launch_bounds__(256) void prep_kernel(const float* __restrict__ xq,
                                                   const float* __restrict__ w,
                                                   float* __restrict__ xqT,
                                                   float* __restrict__ sq) {
    __shared__ float tl[32][33];
    if (blockIdx.x < 896) {
        const int blk = blockIdx.x;               // B * 4 * 7 = 896
        const int b  = blk / 28;
        const int r  = blk - b * 28;
        const int qt = r / 7, et = r - (r / 7) * 7;
        const int q0 = qt * 32, e0 = et * 32;
        const int tx = threadIdx.x & 31, ty = threadIdx.x >> 5;   // 32 x 8
        #pragma unroll
        for (int i = 0; i < 4; ++i) {
            const int q = q0 + ty + 8 * i, e = e0 + tx;
            if (e < E_) tl[ty + 8 * i][tx] = xq[((size_t)b * Q_ + q) * E_ + e];
        }
        __syncthreads();
        #pragma unroll
        for (int i = 0; i < 4; ++i) {
            const int e = e0 + ty + 8 * i, q = q0 + tx;
            if (e < E_) xqT[((size_t)b * E_ + e) * Q_ + q] = tl[tx][ty + 8 * i];
        }
    } else {
        const int wave = (blockIdx.x - 896) * 4 + (threadIdx.x >> 6);  // 0..B*Q-1
        const int lane = threadIdx.x & 63;
        const float* row = xq + (size_t)wave * E_;
        float a = 0.f;
        if (lane < 50) {                                    // 50*4 = 200 = E_
            const f32x4 v  = *(const f32x4*)&row[lane * 4];
            const f32x4 wv = *(const f32x4*)&w[E_ + lane * 4];
            a = (v.x * wv.x + v.y * wv.y) + (v.z * wv.z + v.w * wv.w);
        }
        #pragma unroll
        for (int off = 32; off; off >>= 1) a += __shfl_xor(a, off);
        if (lane == 0) sq[wave] = a;
    }
}

// ---------------------------------------------------------------- K2
// One block per 16 c-rows of one b. 256 threads = 8 c-groups x 32 q-groups,
// each thread owns a 2c x 4q register tile. Softmax fully in registers.
// Same 2-barrier structure as the measured-171us R1 kernel; only TB changed.
__global__ __launch_bounds__(256) void row2_kernel(const float* __restrict__ xc_g,
                                                   const float* __restrict__ xq_g,
                                                   const float* __restrict__ xqT_g,
                                                   const float* __restrict__ w_g,
                                                   const float* __restrict__ sq_g,
                                                   float* __restrict__ m_g,
                                                   float* __restrict__ out) {
    __shared__ float scw3_l[TB][E_];   // 12.8 KB  (xc*w3)
    __shared__ float P_l[TB][Q_];      //  8.0 KB  (normalized softmax probs)
    __shared__ float sc_l[TB];

    const int t    = threadIdx.x;
    const int b    = blockIdx.x >> 7;        // C_/TB = 128 tiles per b
    const int tile = blockIdx.x & 127;
    const int bc0  = b * C_ + tile * TB;

    // ---- phase 0: stage scw3 rows; s_c = xc.w1 (16 lanes per row) ----
    {
        const int r   = t >> 4;              // 0..15
        const int k   = t & 15;              // 0..15
        const int e0  = (k < 8) ? k * 13 : 104 + (k - 8) * 12;
        const int cnt = (k < 8) ? 13 : 12;   // 8*13 + 8*12 = 200
        const float* xc_row = xc_g + (size_t)(bc0 + r) * E_;
        float p1 = 0.f;
        for (int i = 0; i < cnt; ++i) {
            const int e = e0 + i;
            const float v = xc_row[e];
            scw3_l[r][e] = v * w_g[2 * E_ + e];
            p1 = fmaf(v, w_g[e], p1);
        }
        p1 += __shfl_xor(p1, 1);
        p1 += __shfl_xor(p1, 2);
        p1 += __shfl_xor(p1, 4);
        p1 += __shfl_xor(p1, 8);
        if (k == 0) sc_l[r] = p1;
    }
    __syncthreads();

    const int qg = t & 31;
    const int cg = t >> 5;                   // 0..7
    const int c2 = cg * 2;
    const int q4 = qg * 4;

    // ---- phase 1: S[2c][4q] = scw3_tile @ xqT  (xqT reads lane-coalesced) ----
    f32x4 acc[2] = {};
    const float* xqT_b = xqT_g + (size_t)b * E_ * Q_;
    for (int e = 0; e < E_; e += 4) {
        const f32x4 x0 = *(const f32x4*)&xqT_b[(e + 0) * Q_ + q4];
        const f32x4 x1 = *(const f32x4*)&xqT_b[(e + 1) * Q_ + q4];
        const f32x4 x2 = *(const f32x4*)&xqT_b[(e + 2) * Q_ + q4];
        const f32x4 x3 = *(const f32x4*)&xqT_b[(e + 3) * Q_ + q4];
        #pragma unroll
        for (int ci = 0; ci < 2; ++ci) {
            const f32x4 a = *(const f32x4*)&scw3_l[c2 + ci][e];  // broadcast: free
            acc[ci] += a.x * x0 + a.y * x1 + a.z * x2 + a.w * x3;
        }
    }

    // ---- phase 2: in-register softmax over q (reduce across the 32-lane q-group) ----
    const f32x4 sqv = *(const f32x4*)&sq_g[b * Q_ + q4];
    float mx[2], sm[2];
    #pragma unroll
    for (int ci = 0; ci < 2; ++ci) {
        acc[ci] += sc_l[c2 + ci] + sqv;
        mx[ci] = fmaxf(fmaxf(acc[ci].x, acc[ci].y), fmaxf(acc[ci].z, acc[ci].w));
    }
    #pragma unroll
    for (int off = 16; off; off >>= 1) {
        #pragma unroll
        for (int ci = 0; ci < 2; ++ci) mx[ci] = fmaxf(mx[ci], __shfl_xor(mx[ci], off));
    }
    if (qg == 0) {
        #pragma unroll
        for (int ci = 0; ci < 2; ++ci) m_g[bc0 + c2 + ci] = mx[ci];
    }
    #pragma unroll
    for (int ci = 0; ci < 2; ++ci) {
        f32x4 p;
        p.x = __expf(acc[ci].x - mx[ci]);
        p.y = __expf(acc[ci].y - mx[ci]);
        p.z = __expf(acc[ci].z - mx[ci]);
        p.w = __expf(acc[ci].w - mx[ci]);
        acc[ci] = p;
        sm[ci] = (p.x + p.y) + (p.z + p.w);
    }
    #pragma unroll
    for (int off = 16; off; off >>= 1) {
        #pragma unroll
        for (int ci = 0; ci < 2; ++ci) sm[ci] += __shfl_xor(sm[ci], off);
    }
    #pragma unroll
    for (int ci = 0; ci < 2; ++ci) {
        acc[ci] *= (1.f / sm[ci]);
        *(f32x4*)&P_l[c2 + ci][q4] = acc[ci];   // normalized probs
    }
    __syncthreads();

    // ---- phase 3: c2q = P @ xq (xq reads lane-coalesced along e) + epilogue ----
    const float* xq_b = xq_g + (size_t)b * Q_ * E_;
    #pragma unroll
    for (int pass = 0; pass < 2; ++pass) {
        const int e4 = pass * 128 + q4;          // pass1: lanes with e4 >= 200 idle
        if (e4 < E_) {
            f32x4 o[2] = {};
            for (int q = 0; q < Q_; q += 4) {
                const f32x4 xv0 = *(const f32x4*)&xq_b[(q + 0) * E_ + e4];
                const f32x4 xv1 = *(const f32x4*)&xq_b[(q + 1) * E_ + e4];
                const f32x4 xv2 = *(const f32x4*)&xq_b[(q + 2) * E_ + e4];
                const f32x4 xv3 = *(const f32x4*)&xq_b[(q + 3) * E_ + e4];
                #pragma unroll
                for (int ci = 0; ci < 2; ++ci) {
                    const f32x4 p = *(const f32x4*)&P_l[c2 + ci][q];  // broadcast
                    o[ci] += p.x * xv0 + p.y * xv1 + p.z * xv2 + p.w * xv3;
                }
            }
            #pragma unroll
            for (int ci = 0; ci < 2; ++ci) {
                const size_t row = (size_t)(bc0 + c2 + ci);
                const f32x4 xcv = *(const f32x4*)&xc_g[row * E_ + e4];
                float* orow = out + row * (4 * E_);
                *(f32x4*)&orow[e4]          = xcv;
                *(f32x4*)&orow[E_ + e4]     = o[ci];
                *(f32x4*)&orow[2 * E_ + e4] = xcv * o[ci];
            }
        }
    }
}

// ---------------------------------------------------------------- K3
// Fused stats + partial q2c. Each block: global per-b max M over m[b,:]
// (redundant, bitwise-identical across blocks), then its 64-c chunk:
//   part[blk][e] = sum_c exp(m[c]-M)*xc[c][e];  den[blk] = sum_c exp(m[c]-M)
__global__ __launch_bounds__(256) void q2c_partial(const float* __restrict__ xc_g,
                                                   const float* __restrict__ m_g,
                                                   float* __restrict__ part,
                                                   float* __restrict__ den) {
    __shared__ float redl[4];
    __shared__ float wl[64];
    const int blk = blockIdx.x;               // 0..B*32-1
    const int b = blk >> 5, g = blk & 31;     // 32 chunks of 64 c per b
    const int t = threadIdx.x;
    const int c0 = g * 64;

    // global max over m[b, 0:2048]
    float mx = -3.4e38f;
    #pragma unroll
    for (int j = 0; j < 8; ++j) mx = fmaxf(mx, m_g[b * C_ + t + j * 256]);
    #pragma unroll
    for (int off = 32; off; off >>= 1) mx = fmaxf(mx, __shfl_xor(mx, off));
    if ((t & 63) == 0) redl[t >> 6] = mx;
    __syncthreads();
    const float M = fmaxf(fmaxf(redl[0], redl[1]), fmaxf(redl[2], redl[3]));

    if (t < 64) {                              // wave 0: chunk weights
        const float e = __expf(m_g[b * C_ + c0 + t] - M);
        wl[t] = e;
        float s = e;
        #pragma unroll
        for (int off = 32; off; off >>= 1) s += __shfl_xor(s, off);
        if (t == 0) den[blk] = s;
    }
    __syncthreads();

    if (t < E_) {
        float acc = 0.f;
        const float* base = xc_g + ((size_t)(b * C_ + c0)) * E_ + t;
        #pragma unroll 8
        for (int c = 0; c < 64; ++c) acc = fmaf(wl[c], base[(size_t)c * E_], acc);
        part[(size_t)blk * E_ + t] = acc;
    }
}

// ---------------------------------------------------------------- K4
// Fused reduce + segment-3 write. Block = 64 c-rows of one b:
//   q2c[e] = (sum_g part[g][e]) / (sum_g den[g]);  out[...,3E:4E] = xc * q2c
__global__ __launch_bounds__(256) void out4_kernel(const float* __restrict__ xc_g,
                                                   const float* __restrict__ part,
                                                   const float* __restrict__ den,
                                                   float* __restrict__ out) {
    __shared__ float q2c_l[E_];
    __shared__ float invt;
    const int blk = blockIdx.x;               // 0..B*32-1
    const int b = blk >> 5, g = blk & 31;
    const int c0 = g * 64;
    const int t = threadIdx.x;

    if (t < E_) {
        float a = 0.f;
        #pragma unroll
        for (int gg = 0; gg < 32; ++gg) a += part[(size_t)(b * 32 + gg) * E_ + t];
        q2c_l[t] = a;
    }
    if (t >= 224) {                            // lanes 32..63 of wave 3
        float s = den[b * 32 + (t - 224)];
        #pragma unroll
        for (int off = 16; off; off >>= 1) s += __shfl_xor(s, off);
        if (t == 224) invt = 1.f / s;
    }
    __syncthreads();

    const float iv = invt;
    const int e4 = (t % 50) * 4;
    const int r0 = t / 50;                     // 0..4 (t<200), t>=200 idle
    if (t < 200) {
        #pragma unroll
        for (int kk = 0; kk < 16; ++kk) {
            const size_t row = (size_t)(b * C_ + c0 + kk * 4 + r0);
            const f32x4 xcv = *(const f32x4*)&xc_g[row * E_ + e4];
            const f32x4 qv  = *(const f32x4*)&q2c_l[e4];
            *(f32x4*)&out[row * (4 * E_) + 3 * E_ + e4] = xcv * (qv * iv);
        }
    }
}

extern "C" void kernel_launch(void* const* d_in, const int* in_sizes, int n_in,
                              void* d_out, int out_size, void* d_ws, size_t ws_size,
                              hipStream_t stream) {
    // order-robust input selection by element count
    const float* xc = (const float*)d_in[0];
    const float* xq = (const float*)d_in[1];
    const float* w  = (const float*)d_in[2];
    for (int i = 0; i < n_in; ++i) {
        if      (in_sizes[i] == B_ * C_ * E_) xc = (const float*)d_in[i];
        else if (in_sizes[i] == B_ * Q_ * E_) xq = (const float*)d_in[i];
        else if (in_sizes[i] == 3 * E_)       w  = (const float*)d_in[i];
    }
    float* out = (float*)d_out;

    float* ws    = (float*)d_ws;
    float* sq    = ws;                 // B*Q   = 4096
    float* m     = sq + B_ * Q_;       // B*C   = 65536
    float* xqT   = m + B_ * C_;        // B*E*Q = 819200  (~3.3 MB)
    // part/den alias xqT: written only AFTER row2's last xqT read (stream-ordered);
    // 1024*200 + 1024 = 205824 floats fits well inside xqT's 819200.
    float* part  = xqT;                            // [B*32][E_]
    float* den   = xqT + 1024 * E_;                // [B*32]

    prep_kernel <<<1920,               256, 0, stream>>>(xq, w, xqT, sq);
    row2_kernel <<<B_ * (C_ / TB),     256, 0, stream>>>(xc, xq, xqT, w, sq, m, out);
    q2c_partial <<<B_ * 32,            256, 0, stream>>>(xc, m, part, den);
    out4_kernel <<<B_ * 32,            256, 0, stream>>>(xc, part, den, out);
}

// Round 5
// 404.536 us; speedup vs baseline: 1.2747x; 1.2747x over previous
//
#include <hip/hip_runtime.h>

// Problem: B=32, C=2048, Q=128, E=200. Inputs fp32, OUTPUT fp32 (B,C,4E).
// R2 post-mortem: XCD swizzle + LDS aliasing in row2 REGRESSED; reverted.
// R3 post-mortem: tail is ~218-237us across 4-6 launches; kernel-time sum ~40us.
// R4 post-mortem: row2 TB 32->16 REGRESSED 170->298 (bank conflicts 0->786K,
//   per-block critical path unchanged while per-block output halved, xq/xqT
//   L2 traffic doubled). Occupancy ~10 waves/CU regardless of LDS cap (R2+R4:
//   occupancy lever falsified twice).
// R5: exact R1 row2 (measured 170us twice) + R4's 4-kernel tail (measured 218us).
#define B_ 32
#define C_ 2048
#define Q_ 128
#define E_ 200
#define TB 32    // c-rows per block in row2_kernel

typedef __attribute__((ext_vector_type(4))) float f32x4;

// ---------------------------------------------------------------- K0: prep
// blocks 0..895:    xqT[b][e][q] = xq[b][q][e] via padded-LDS 32x32 tile
// blocks 896..1919: s_q[b,q] = dot(xq[b,q,:], w2), one wave per q-row
__global__ __launch_bounds__(256) void prep_kernel(const float* __restrict__ xq,
                                                   const float* __restrict__ w,
                                                   float* __restrict__ xqT,
                                                   float* __restrict__ sq) {
    __shared__ float tl[32][33];
    if (blockIdx.x < 896) {
        const int blk = blockIdx.x;               // B * 4 * 7 = 896
        const int b  = blk / 28;
        const int r  = blk - b * 28;
        const int qt = r / 7, et = r - (r / 7) * 7;
        const int q0 = qt * 32, e0 = et * 32;
        const int tx = threadIdx.x & 31, ty = threadIdx.x >> 5;   // 32 x 8
        #pragma unroll
        for (int i = 0; i < 4; ++i) {
            const int q = q0 + ty + 8 * i, e = e0 + tx;
            if (e < E_) tl[ty + 8 * i][tx] = xq[((size_t)b * Q_ + q) * E_ + e];
        }
        __syncthreads();
        #pragma unroll
        for (int i = 0; i < 4; ++i) {
            const int e = e0 + ty + 8 * i, q = q0 + tx;
            if (e < E_) xqT[((size_t)b * E_ + e) * Q_ + q] = tl[tx][ty + 8 * i];
        }
    } else {
        const int wave = (blockIdx.x - 896) * 4 + (threadIdx.x >> 6);  // 0..B*Q-1
        const int lane = threadIdx.x & 63;
        const float* row = xq + (size_t)wave * E_;
        float a = 0.f;
        if (lane < 50) {                                    // 50*4 = 200 = E_
            const f32x4 v  = *(const f32x4*)&row[lane * 4];
            const f32x4 wv = *(const f32x4*)&w[E_ + lane * 4];
            a = (v.x * wv.x + v.y * wv.y) + (v.z * wv.z + v.w * wv.w);
        }
        #pragma unroll
        for (int off = 32; off; off >>= 1) a += __shfl_xor(a, off);
        if (lane == 0) sq[wave] = a;
    }
}

// ---------------------------------------------------------------- K2  (exact R1)
// One block per 32 c-rows of one b. 256 threads = 8 c-groups x 32 q-groups,
// each thread owns a 4c x 4q register tile. Softmax fully in registers.
__global__ __launch_bounds__(256) void row2_kernel(const float* __restrict__ xc_g,
                                                   const float* __restrict__ xq_g,
                                                   const float* __restrict__ xqT_g,
                                                   const float* __restrict__ w_g,
                                                   const float* __restrict__ sq_g,
                                                   float* __restrict__ m_g,
                                                   float* __restrict__ out) {
    __shared__ float scw3_l[TB][E_];   // 25.6 KB  (xc*w3)
    __shared__ float P_l[TB][Q_];      // 16.0 KB  (normalized softmax probs)
    __shared__ float sc_l[TB];

    const int t    = threadIdx.x;
    const int b    = blockIdx.x >> 6;        // C_/TB = 64 tiles per b
    const int tile = blockIdx.x & 63;
    const int bc0  = b * C_ + tile * TB;

    // ---- phase 0: stage scw3 rows; s_c = xc.w1 (8 lanes per row) ----
    {
        const int r  = t >> 3;               // 0..31
        const int k  = t & 7;                // 0..7
        const int e0 = k * 25;
        const float* xc_row = xc_g + (size_t)(bc0 + r) * E_;
        float p1 = 0.f;
        #pragma unroll
        for (int i = 0; i < 25; ++i) {
            const int e = e0 + i;
            const float v = xc_row[e];
            scw3_l[r][e] = v * w_g[2 * E_ + e];
            p1 = fmaf(v, w_g[e], p1);
        }
        p1 += __shfl_xor(p1, 1);
        p1 += __shfl_xor(p1, 2);
        p1 += __shfl_xor(p1, 4);
        if (k == 0) sc_l[r] = p1;
    }
    __syncthreads();

    const int qg = t & 31;
    const int cg = t >> 5;                   // 0..7
    const int c4 = cg * 4;
    const int q4 = qg * 4;

    // ---- phase 1: S[4c][4q] = scw3_tile @ xqT  (xqT reads lane-coalesced) ----
    f32x4 acc[4] = {};
    const float* xqT_b = xqT_g + (size_t)b * E_ * Q_;
    for (int e = 0; e < E_; e += 4) {
        const f32x4 x0 = *(const f32x4*)&xqT_b[(e + 0) * Q_ + q4];
        const f32x4 x1 = *(const f32x4*)&xqT_b[(e + 1) * Q_ + q4];
        const f32x4 x2 = *(const f32x4*)&xqT_b[(e + 2) * Q_ + q4];
        const f32x4 x3 = *(const f32x4*)&xqT_b[(e + 3) * Q_ + q4];
        #pragma unroll
        for (int ci = 0; ci < 4; ++ci) {
            const f32x4 a = *(const f32x4*)&scw3_l[c4 + ci][e];  // broadcast: free
            acc[ci] += a.x * x0 + a.y * x1 + a.z * x2 + a.w * x3;
        }
    }

    // ---- phase 2: in-register softmax over q (reduce across the 32-lane q-group) ----
    const f32x4 sqv = *(const f32x4*)&sq_g[b * Q_ + q4];
    float mx[4], sm[4];
    #pragma unroll
    for (int ci = 0; ci < 4; ++ci) {
        acc[ci] += sc_l[c4 + ci] + sqv;
        mx[ci] = fmaxf(fmaxf(acc[ci].x, acc[ci].y), fmaxf(acc[ci].z, acc[ci].w));
    }
    #pragma unroll
    for (int off = 16; off; off >>= 1) {
        #pragma unroll
        for (int ci = 0; ci < 4; ++ci) mx[ci] = fmaxf(mx[ci], __shfl_xor(mx[ci], off));
    }
    if (qg == 0) {
        #pragma unroll
        for (int ci = 0; ci < 4; ++ci) m_g[bc0 + c4 + ci] = mx[ci];
    }
    #pragma unroll
    for (int ci = 0; ci < 4; ++ci) {
        f32x4 p;
        p.x = __expf(acc[ci].x - mx[ci]);
        p.y = __expf(acc[ci].y - mx[ci]);
        p.z = __expf(acc[ci].z - mx[ci]);
        p.w = __expf(acc[ci].w - mx[ci]);
        acc[ci] = p;
        sm[ci] = (p.x + p.y) + (p.z + p.w);
    }
    #pragma unroll
    for (int off = 16; off; off >>= 1) {
        #pragma unroll
        for (int ci = 0; ci < 4; ++ci) sm[ci] += __shfl_xor(sm[ci], off);
    }
    #pragma unroll
    for (int ci = 0; ci < 4; ++ci) {
        acc[ci] *= (1.f / sm[ci]);
        *(f32x4*)&P_l[c4 + ci][q4] = acc[ci];   // normalized probs
    }
    __syncthreads();

    // ---- phase 3: c2q = P @ xq (xq reads lane-coalesced along e) + epilogue ----
    const float* xq_b = xq_g + (size_t)b * Q_ * E_;
    #pragma unroll
    for (int pass = 0; pass < 2; ++pass) {
        const int e4 = pass * 128 + q4;          // pass1: lanes with e4 >= 200 idle
        if (e4 < E_) {
            f32x4 o[4] = {};
            for (int q = 0; q < Q_; q += 4) {
                const f32x4 xv0 = *(const f32x4*)&xq_b[(q + 0) * E_ + e4];
                const f32x4 xv1 = *(const f32x4*)&xq_b[(q + 1) * E_ + e4];
                const f32x4 xv2 = *(const f32x4*)&xq_b[(q + 2) * E_ + e4];
                const f32x4 xv3 = *(const f32x4*)&xq_b[(q + 3) * E_ + e4];
                #pragma unroll
                for (int ci = 0; ci < 4; ++ci) {
                    const f32x4 p = *(const f32x4*)&P_l[c4 + ci][q];  // broadcast
                    o[ci] += p.x * xv0 + p.y * xv1 + p.z * xv2 + p.w * xv3;
                }
            }
            #pragma unroll
            for (int ci = 0; ci < 4; ++ci) {
                const size_t row = (size_t)(bc0 + c4 + ci);
                const f32x4 xcv = *(const f32x4*)&xc_g[row * E_ + e4];
                float* orow = out + row * (4 * E_);
                *(f32x4*)&orow[e4]          = xcv;
                *(f32x4*)&orow[E_ + e4]     = o[ci];
                *(f32x4*)&orow[2 * E_ + e4] = xcv * o[ci];
            }
        }
    }
}

// ---------------------------------------------------------------- K3
// Fused stats + partial q2c. Each block: global per-b max M over m[b,:]
// (redundant, bitwise-identical across blocks), then its 64-c chunk:
//   part[blk][e] = sum_c exp(m[c]-M)*xc[c][e];  den[blk] = sum_c exp(m[c]-M)
__global__ __launch_bounds__(256) void q2c_partial(const float* __restrict__ xc_g,
                                                   const float* __restrict__ m_g,
                                                   float* __restrict__ part,
                                                   float* __restrict__ den) {
    __shared__ float redl[4];
    __shared__ float wl[64];
    const int blk = blockIdx.x;               // 0..B*32-1
    const int b = blk >> 5, g = blk & 31;     // 32 chunks of 64 c per b
    const int t = threadIdx.x;
    const int c0 = g * 64;

    // global max over m[b, 0:2048]
    float mx = -3.4e38f;
    #pragma unroll
    for (int j = 0; j < 8; ++j) mx = fmaxf(mx, m_g[b * C_ + t + j * 256]);
    #pragma unroll
    for (int off = 32; off; off >>= 1) mx = fmaxf(mx, __shfl_xor(mx, off));
    if ((t & 63) == 0) redl[t >> 6] = mx;
    __syncthreads();
    const float M = fmaxf(fmaxf(redl[0], redl[1]), fmaxf(redl[2], redl[3]));

    if (t < 64) {                              // wave 0: chunk weights
        const float e = __expf(m_g[b * C_ + c0 + t] - M);
        wl[t] = e;
        float s = e;
        #pragma unroll
        for (int off = 32; off; off >>= 1) s += __shfl_xor(s, off);
        if (t == 0) den[blk] = s;
    }
    __syncthreads();

    if (t < E_) {
        float acc = 0.f;
        const float* base = xc_g + ((size_t)(b * C_ + c0)) * E_ + t;
        #pragma unroll 8
        for (int c = 0; c < 64; ++c) acc = fmaf(wl[c], base[(size_t)c * E_], acc);
        part[(size_t)blk * E_ + t] = acc;
    }
}

// ---------------------------------------------------------------- K4
// Fused reduce + segment-3 write. Block = 64 c-rows of one b:
//   q2c[e] = (sum_g part[g][e]) / (sum_g den[g]);  out[...,3E:4E] = xc * q2c
__global__ __launch_bounds__(256) void out4_kernel(const float* __restrict__ xc_g,
                                                   const float* __restrict__ part,
                                                   const float* __restrict__ den,
                                                   float* __restrict__ out) {
    __shared__ float q2c_l[E_];
    __shared__ float invt;
    const int blk = blockIdx.x;               // 0..B*32-1
    const int b = blk >> 5, g = blk & 31;
    const int c0 = g * 64;
    const int t = threadIdx.x;

    if (t < E_) {
        float a = 0.f;
        #pragma unroll
        for (int gg = 0; gg < 32; ++gg) a += part[(size_t)(b * 32 + gg) * E_ + t];
        q2c_l[t] = a;
    }
    if (t >= 224) {                            // lanes 32..63 of wave 3
        float s = den[b * 32 + (t - 224)];
        #pragma unroll
        for (int off = 16; off; off >>= 1) s += __shfl_xor(s, off);
        if (t == 224) invt = 1.f / s;
    }
    __syncthreads();

    const float iv = invt;
    const int e4 = (t % 50) * 4;
    const int r0 = t / 50;                     // 0..3 (t<200), t>=200 idle
    if (t < 200) {
        #pragma unroll
        for (int kk = 0; kk < 16; ++kk) {
            const size_t row = (size_t)(b * C_ + c0 + kk * 4 + r0);
            const f32x4 xcv = *(const f32x4*)&xc_g[row * E_ + e4];
            const f32x4 qv  = *(const f32x4*)&q2c_l[e4];
            *(f32x4*)&out[row * (4 * E_) + 3 * E_ + e4] = xcv * (qv * iv);
        }
    }
}

extern "C" void kernel_launch(void* const* d_in, const int* in_sizes, int n_in,
                              void* d_out, int out_size, void* d_ws, size_t ws_size,
                              hipStream_t stream) {
    // order-robust input selection by element count
    const float* xc = (const float*)d_in[0];
    const float* xq = (const float*)d_in[1];
    const float* w  = (const float*)d_in[2];
    for (int i = 0; i < n_in; ++i) {
        if      (in_sizes[i] == B_ * C_ * E_) xc = (const float*)d_in[i];
        else if (in_sizes[i] == B_ * Q_ * E_) xq = (const float*)d_in[i];
        else if (in_sizes[i] == 3 * E_)       w  = (const float*)d_in[i];
    }
    float* out = (float*)d_out;

    float* ws    = (float*)d_ws;
    float* sq    = ws;                 // B*Q   = 4096
    float* m     = sq + B_ * Q_;       // B*C   = 65536
    float* xqT   = m + B_ * C_;        // B*E*Q = 819200  (~3.3 MB)
    // part/den alias xqT: written only AFTER row2's last xqT read (stream-ordered);
    // 1024*200 + 1024 = 205824 floats fits well inside xqT's 819200.
    float* part  = xqT;                            // [B*32][E_]
    float* den   = xqT + 1024 * E_;                // [B*32]

    prep_kernel <<<1920,               256, 0, stream>>>(xq, w, xqT, sq);
    row2_kernel <<<B_ * (C_ / TB),     256, 0, stream>>>(xc, xq, xqT, w, sq, m, out);
    q2c_partial <<<B_ * 32,            256, 0, stream>>>(xc, m, part, den);
    out4_kernel <<<B_ * 32,            256, 0, stream>>>(xc, part, den, out);
}

// Round 7
// 395.170 us; speedup vs baseline: 1.3049x; 1.0237x over previous
//
#include <hip/hip_runtime.h>

// Problem: B=32, C=2048, Q=128, E=200. Inputs fp32, OUTPUT fp32 (B,C,4E).
// R4: row2 TB16 regressed; occupancy lever falsified twice (R2,R4).
// R5: 404.5us = row2 170.7 + our-tail ~50 + ~180us fixed harness floor
//   (Dispatch_Id spacing shows ~9 dispatches/iter vs our 4: harness reset
//   memsets incl. 209MB out-zero are inside the measured window).
// R6: cooperative kernel HUNG THE CONTAINER (grid.sync residency deadlock).
//   Cooperative launch retired for this session.
// R7: single-variable experiment on row2: XCD swizzle ONLY (R2 bundled it
//   with LDS aliasing which regressed; FETCH 82->55MB proved the mechanism).
//   Theory: without swizzle each XCD L2 (4MB) must cache 32 b-panels (6.5MB)
//   -> thrash -> xqT/xq loads at L3 latency (~600cyc); with swizzle 4 b's/XCD
//   (820KB) -> L2-resident (~200cyc). row2 is latency-bound (per-wave VALU
//   duty ~19%), so this should cut the stall directly.
#define B_ 32
#define C_ 2048
#define Q_ 128
#define E_ 200
#define TB 32

typedef __attribute__((ext_vector_type(4))) float f32x4;

// ---------------------------------------------------------------- K0: prep
// blocks 0..895:    xqT[b][e][q] = xq[b][q][e] via padded-LDS 32x32 tile
// blocks 896..1919: s_q[b,q] = dot(xq[b,q,:], w2), one wave per q-row
__global__ __launch_bounds__(256) void prep_kernel(const float* __restrict__ xq,
                                                   const float* __restrict__ w,
                                                   float* __restrict__ xqT,
                                                   float* __restrict__ sq) {
    __shared__ float tl[32][33];
    if (blockIdx.x < 896) {
        const int blk = blockIdx.x;               // B * 4 * 7 = 896
        const int b  = blk / 28;
        const int r  = blk - b * 28;
        const int qt = r / 7, et = r - (r / 7) * 7;
        const int q0 = qt * 32, e0 = et * 32;
        const int tx = threadIdx.x & 31, ty = threadIdx.x >> 5;   // 32 x 8
        #pragma unroll
        for (int i = 0; i < 4; ++i) {
            const int q = q0 + ty + 8 * i, e = e0 + tx;
            if (e < E_) tl[ty + 8 * i][tx] = xq[((size_t)b * Q_ + q) * E_ + e];
        }
        __syncthreads();
        #pragma unroll
        for (int i = 0; i < 4; ++i) {
            const int e = e0 + ty + 8 * i, q = q0 + tx;
            if (e < E_) xqT[((size_t)b * E_ + e) * Q_ + q] = tl[tx][ty + 8 * i];
        }
    } else {
        const int wave = (blockIdx.x - 896) * 4 + (threadIdx.x >> 6);  // 0..B*Q-1
        const int lane = threadIdx.x & 63;
        const float* row = xq + (size_t)wave * E_;
        float a = 0.f;
        if (lane < 50) {                                    // 50*4 = 200 = E_
            const f32x4 v  = *(const f32x4*)&row[lane * 4];
            const f32x4 wv = *(const f32x4*)&w[E_ + lane * 4];
            a = (v.x * wv.x + v.y * wv.y) + (v.z * wv.z + v.w * wv.w);
        }
        #pragma unroll
        for (int off = 32; off; off >>= 1) a += __shfl_xor(a, off);
        if (lane == 0) sq[wave] = a;
    }
}

// ---------------------------------------------------------------- K2
// R1 row2 (measured 170us twice) + XCD-aware block->(b,tile) mapping ONLY.
// All 64 tiles of one b land on one XCD (blk%8 fixed): 4 b-panels per L2.
__global__ __launch_bounds__(256) void row2_kernel(const float* __restrict__ xc_g,
                                                   const float* __restrict__ xq_g,
                                                   const float* __restrict__ xqT_g,
                                                   const float* __restrict__ w_g,
                                                   const float* __restrict__ sq_g,
                                                   float* __restrict__ m_g,
                                                   float* __restrict__ out) {
    __shared__ float scw3_l[TB][E_];   // 25.6 KB  (xc*w3)
    __shared__ float P_l[TB][Q_];      // 16.0 KB  (normalized softmax probs)
    __shared__ float sc_l[TB];

    const int t    = threadIdx.x;
    // XCD swizzle (bijective, 2048 blocks): x = XCD slot, 4 b's per XCD.
    const int blk  = blockIdx.x;
    const int x    = blk & 7;
    const int g    = blk >> 3;               // 0..255
    const int b    = x * 4 + (g >> 6);
    const int tile = g & 63;
    const int bc0  = b * C_ + tile * TB;

    // ---- phase 0: stage scw3 rows; s_c = xc.w1 (8 lanes per row) ----
    {
        const int r  = t >> 3;               // 0..31
        const int k  = t & 7;                // 0..7
        const int e0 = k * 25;
        const float* xc_row = xc_g + (size_t)(bc0 + r) * E_;
        float p1 = 0.f;
        #pragma unroll
        for (int i = 0; i < 25; ++i) {
            const int e = e0 + i;
            const float v = xc_row[e];
            scw3_l[r][e] = v * w_g[2 * E_ + e];
            p1 = fmaf(v, w_g[e], p1);
        }
        p1 += __shfl_xor(p1, 1);
        p1 += __shfl_xor(p1, 2);
        p1 += __shfl_xor(p1, 4);
        if (k == 0) sc_l[r] = p1;
    }
    __syncthreads();

    const int qg = t & 31;
    const int cg = t >> 5;                   // 0..7
    const int c4 = cg * 4;
    const int q4 = qg * 4;

    // ---- phase 1: S[4c][4q] = scw3_tile @ xqT  (xqT reads lane-coalesced) ----
    f32x4 acc[4] = {};
    const float* xqT_b = xqT_g + (size_t)b * E_ * Q_;
    for (int e = 0; e < E_; e += 4) {
        const f32x4 x0 = *(const f32x4*)&xqT_b[(e + 0) * Q_ + q4];
        const f32x4 x1 = *(const f32x4*)&xqT_b[(e + 1) * Q_ + q4];
        const f32x4 x2 = *(const f32x4*)&xqT_b[(e + 2) * Q_ + q4];
        const f32x4 x3 = *(const f32x4*)&xqT_b[(e + 3) * Q_ + q4];
        #pragma unroll
        for (int ci = 0; ci < 4; ++ci) {
            const f32x4 a = *(const f32x4*)&scw3_l[c4 + ci][e];  // broadcast: free
            acc[ci] += a.x * x0 + a.y * x1 + a.z * x2 + a.w * x3;
        }
    }

    // ---- phase 2: in-register softmax over q (reduce across the 32-lane q-group) ----
    const f32x4 sqv = *(const f32x4*)&sq_g[b * Q_ + q4];
    float mx[4], sm[4];
    #pragma unroll
    for (int ci = 0; ci < 4; ++ci) {
        acc[ci] += sc_l[c4 + ci] + sqv;
        mx[ci] = fmaxf(fmaxf(acc[ci].x, acc[ci].y), fmaxf(acc[ci].z, acc[ci].w));
    }
    #pragma unroll
    for (int off = 16; off; off >>= 1) {
        #pragma unroll
        for (int ci = 0; ci < 4; ++ci) mx[ci] = fmaxf(mx[ci], __shfl_xor(mx[ci], off));
    }
    if (qg == 0) {
        #pragma unroll
        for (int ci = 0; ci < 4; ++ci) m_g[bc0 + c4 + ci] = mx[ci];
    }
    #pragma unroll
    for (int ci = 0; ci < 4; ++ci) {
        f32x4 p;
        p.x = __expf(acc[ci].x - mx[ci]);
        p.y = __expf(acc[ci].y - mx[ci]);
        p.z = __expf(acc[ci].z - mx[ci]);
        p.w = __expf(acc[ci].w - mx[ci]);
        acc[ci] = p;
        sm[ci] = (p.x + p.y) + (p.z + p.w);
    }
    #pragma unroll
    for (int off = 16; off; off >>= 1) {
        #pragma unroll
        for (int ci = 0; ci < 4; ++ci) sm[ci] += __shfl_xor(sm[ci], off);
    }
    #pragma unroll
    for (int ci = 0; ci < 4; ++ci) {
        acc[ci] *= (1.f / sm[ci]);
        *(f32x4*)&P_l[c4 + ci][q4] = acc[ci];   // normalized probs
    }
    __syncthreads();

    // ---- phase 3: c2q = P @ xq (xq reads lane-coalesced along e) + epilogue ----
    const float* xq_b = xq_g + (size_t)b * Q_ * E_;
    #pragma unroll
    for (int pass = 0; pass < 2; ++pass) {
        const int e4 = pass * 128 + q4;          // pass1: lanes with e4 >= 200 idle
        if (e4 < E_) {
            f32x4 o[4] = {};
            for (int q = 0; q < Q_; q += 4) {
                const f32x4 xv0 = *(const f32x4*)&xq_b[(q + 0) * E_ + e4];
                const f32x4 xv1 = *(const f32x4*)&xq_b[(q + 1) * E_ + e4];
                const f32x4 xv2 = *(const f32x4*)&xq_b[(q + 2) * E_ + e4];
                const f32x4 xv3 = *(const f32x4*)&xq_b[(q + 3) * E_ + e4];
                #pragma unroll
                for (int ci = 0; ci < 4; ++ci) {
                    const f32x4 p = *(const f32x4*)&P_l[c4 + ci][q];  // broadcast
                    o[ci] += p.x * xv0 + p.y * xv1 + p.z * xv2 + p.w * xv3;
                }
            }
            #pragma unroll
            for (int ci = 0; ci < 4; ++ci) {
                const size_t row = (size_t)(bc0 + c4 + ci);
                const f32x4 xcv = *(const f32x4*)&xc_g[row * E_ + e4];
                float* orow = out + row * (4 * E_);
                *(f32x4*)&orow[e4]          = xcv;
                *(f32x4*)&orow[E_ + e4]     = o[ci];
                *(f32x4*)&orow[2 * E_ + e4] = xcv * o[ci];
            }
        }
    }
}

// ---------------------------------------------------------------- K3
// Fused stats + partial q2c. Each block: global per-b max M over m[b,:]
// (redundant, bitwise-identical across blocks), then its 64-c chunk:
//   part[blk][e] = sum_c exp(m[c]-M)*xc[c][e];  den[blk] = sum_c exp(m[c]-M)
__global__ __launch_bounds__(256) void q2c_partial(const float* __restrict__ xc_g,
                                                   const float* __restrict__ m_g,
                                                   float* __restrict__ part,
                                                   float* __restrict__ den) {
    __shared__ float redl[4];
    __shared__ float wl[64];
    const int blk = blockIdx.x;               // 0..B*32-1
    const int b = blk >> 5, g = blk & 31;     // 32 chunks of 64 c per b
    const int t = threadIdx.x;
    const int c0 = g * 64;

    // global max over m[b, 0:2048]
    float mx = -3.4e38f;
    #pragma unroll
    for (int j = 0; j < 8; ++j) mx = fmaxf(mx, m_g[b * C_ + t + j * 256]);
    #pragma unroll
    for (int off = 32; off; off >>= 1) mx = fmaxf(mx, __shfl_xor(mx, off));
    if ((t & 63) == 0) redl[t >> 6] = mx;
    __syncthreads();
    const float M = fmaxf(fmaxf(redl[0], redl[1]), fmaxf(redl[2], redl[3]));

    if (t < 64) {                              // wave 0: chunk weights
        const float e = __expf(m_g[b * C_ + c0 + t] - M);
        wl[t] = e;
        float s = e;
        #pragma unroll
        for (int off = 32; off; off >>= 1) s += __shfl_xor(s, off);
        if (t == 0) den[blk] = s;
    }
    __syncthreads();

    if (t < E_) {
        float acc = 0.f;
        const float* base = xc_g + ((size_t)(b * C_ + c0)) * E_ + t;
        #pragma unroll 8
        for (int c = 0; c < 64; ++c) acc = fmaf(wl[c], base[(size_t)c * E_], acc);
        part[(size_t)blk * E_ + t] = acc;
    }
}

// ---------------------------------------------------------------- K4
// Fused reduce + segment-3 write. Block = 64 c-rows of one b:
//   q2c[e] = (sum_g part[g][e]) / (sum_g den[g]);  out[...,3E:4E] = xc * q2c
__global__ __launch_bounds__(256) void out4_kernel(const float* __restrict__ xc_g,
                                                   const float* __restrict__ part,
                                                   const float* __restrict__ den,
                                                   float* __restrict__ out) {
    __shared__ float q2c_l[E_];
    __shared__ float invt;
    const int blk = blockIdx.x;               // 0..B*32-1
    const int b = blk >> 5, g = blk & 31;
    const int c0 = g * 64;
    const int t = threadIdx.x;

    if (t < E_) {
        float a = 0.f;
        #pragma unroll
        for (int gg = 0; gg < 32; ++gg) a += part[(size_t)(b * 32 + gg) * E_ + t];
        q2c_l[t] = a;
    }
    if (t >= 224) {                            // lanes 32..63 of wave 3
        float s = den[b * 32 + (t - 224)];
        #pragma unroll
        for (int off = 16; off; off >>= 1) s += __shfl_xor(s, off);
        if (t == 224) invt = 1.f / s;
    }
    __syncthreads();

    const float iv = invt;
    const int e4 = (t % 50) * 4;
    const int r0 = t / 50;                     // 0..3 (t<200), t>=200 idle
    if (t < 200) {
        #pragma unroll
        for (int kk = 0; kk < 16; ++kk) {
            const size_t row = (size_t)(b * C_ + c0 + kk * 4 + r0);
            const f32x4 xcv = *(const f32x4*)&xc_g[row * E_ + e4];
            const f32x4 qv  = *(const f32x4*)&q2c_l[e4];
            *(f32x4*)&out[row * (4 * E_) + 3 * E_ + e4] = xcv * (qv * iv);
        }
    }
}

extern "C" void kernel_launch(void* const* d_in, const int* in_sizes, int n_in,
                              void* d_out, int out_size, void* d_ws, size_t ws_size,
                              hipStream_t stream) {
    // order-robust input selection by element count
    const float* xc = (const float*)d_in[0];
    const float* xq = (const float*)d_in[1];
    const float* w  = (const float*)d_in[2];
    for (int i = 0; i < n_in; ++i) {
        if      (in_sizes[i] == B_ * C_ * E_) xc = (const float*)d_in[i];
        else if (in_sizes[i] == B_ * Q_ * E_) xq = (const float*)d_in[i];
        else if (in_sizes[i] == 3 * E_)       w  = (const float*)d_in[i];
    }
    float* out = (float*)d_out;

    float* ws    = (float*)d_ws;
    float* sq    = ws;                 // B*Q   = 4096
    float* m     = sq + B_ * Q_;       // B*C   = 65536
    float* xqT   = m + B_ * C_;        // B*E*Q = 819200  (~3.3 MB)
    // part/den alias xqT: written only AFTER row2's last xqT read (stream-ordered);
    // 1024*200 + 1024 = 205824 floats fits well inside xqT's 819200.
    float* part  = xqT;                            // [B*32][E_]
    float* den   = xqT + 1024 * E_;                // [B*32]

    prep_kernel <<<1920,               256, 0, stream>>>(xq, w, xqT, sq);
    row2_kernel <<<B_ * (C_ / TB),     256, 0, stream>>>(xc, xq, xqT, w, sq, m, out);
    q2c_partial <<<B_ * 32,            256, 0, stream>>>(xc, m, part, den);
    out4_kernel <<<B_ * 32,            256, 0, stream>>>(xc, part, den, out);
}

// Round 8
// 390.510 us; speedup vs baseline: 1.3204x; 1.0119x over previous
//
#include <hip/hip_runtime.h>

// Problem: B=32, C=2048, Q=128, E=200. Inputs fp32, OUTPUT fp32 (B,C,4E).
// Ledger: R2/R4 occupancy lever falsified; R6 cooperative hang (retired);
// R7 swizzle-only: FETCH 82->55MB but dur FLAT -> L2-latency theory falsified.
// Residual theory: per-wave vmcnt stalls in phases 1/3 (VALU-issue ~85us/CU
// vs 170us wall). R8: 2-deep software pipeline (register prefetch) in phases
// 1 and 3 + hoist phase-3's first loads above the P_l barrier. Single variable;
// swizzle kept; tail identical to R7.
#define B_ 32
#define C_ 2048
#define Q_ 128
#define E_ 200
#define TB 32

typedef __attribute__((ext_vector_type(4))) float f32x4;

// ---------------------------------------------------------------- K0: prep
// blocks 0..895:    xqT[b][e][q] = xq[b][q][e] via padded-LDS 32x32 tile
// blocks 896..1919: s_q[b,q] = dot(xq[b,q,:], w2), one wave per q-row
__global__ __launch_bounds__(256) void prep_kernel(const float* __restrict__ xq,
                                                   const float* __restrict__ w,
                                                   float* __restrict__ xqT,
                                                   float* __restrict__ sq) {
    __shared__ float tl[32][33];
    if (blockIdx.x < 896) {
        const int blk = blockIdx.x;               // B * 4 * 7 = 896
        const int b  = blk / 28;
        const int r  = blk - b * 28;
        const int qt = r / 7, et = r - (r / 7) * 7;
        const int q0 = qt * 32, e0 = et * 32;
        const int tx = threadIdx.x & 31, ty = threadIdx.x >> 5;   // 32 x 8
        #pragma unroll
        for (int i = 0; i < 4; ++i) {
            const int q = q0 + ty + 8 * i, e = e0 + tx;
            if (e < E_) tl[ty + 8 * i][tx] = xq[((size_t)b * Q_ + q) * E_ + e];
        }
        __syncthreads();
        #pragma unroll
        for (int i = 0; i < 4; ++i) {
            const int e = e0 + ty + 8 * i, q = q0 + tx;
            if (e < E_) xqT[((size_t)b * E_ + e) * Q_ + q] = tl[tx][ty + 8 * i];
        }
    } else {
        const int wave = (blockIdx.x - 896) * 4 + (threadIdx.x >> 6);  // 0..B*Q-1
        const int lane = threadIdx.x & 63;
        const float* row = xq + (size_t)wave * E_;
        float a = 0.f;
        if (lane < 50) {                                    // 50*4 = 200 = E_
            const f32x4 v  = *(const f32x4*)&row[lane * 4];
            const f32x4 wv = *(const f32x4*)&w[E_ + lane * 4];
            a = (v.x * wv.x + v.y * wv.y) + (v.z * wv.z + v.w * wv.w);
        }
        #pragma unroll
        for (int off = 32; off; off >>= 1) a += __shfl_xor(a, off);
        if (lane == 0) sq[wave] = a;
    }
}

// ---------------------------------------------------------------- K2
// R7 row2 (swizzle kept) + 2-deep register-prefetch pipeline in phases 1/3.
__global__ __launch_bounds__(256) void row2_kernel(const float* __restrict__ xc_g,
                                                   const float* __restrict__ xq_g,
                                                   const float* __restrict__ xqT_g,
                                                   const float* __restrict__ w_g,
                                                   const float* __restrict__ sq_g,
                                                   float* __restrict__ m_g,
                                                   float* __restrict__ out) {
    __shared__ float scw3_l[TB][E_];   // 25.6 KB  (xc*w3)
    __shared__ float P_l[TB][Q_];      // 16.0 KB  (normalized softmax probs)
    __shared__ float sc_l[TB];

    const int t    = threadIdx.x;
    // XCD swizzle (bijective, 2048 blocks): all 64 tiles of one b on one XCD.
    const int blk  = blockIdx.x;
    const int x    = blk & 7;
    const int g    = blk >> 3;               // 0..255
    const int b    = x * 4 + (g >> 6);
    const int tile = g & 63;
    const int bc0  = b * C_ + tile * TB;

    // ---- phase 0: stage scw3 rows; s_c = xc.w1 (8 lanes per row) ----
    {
        const int r  = t >> 3;               // 0..31
        const int k  = t & 7;                // 0..7
        const int e0 = k * 25;
        const float* xc_row = xc_g + (size_t)(bc0 + r) * E_;
        float p1 = 0.f;
        #pragma unroll
        for (int i = 0; i < 25; ++i) {
            const int e = e0 + i;
            const float v = xc_row[e];
            scw3_l[r][e] = v * w_g[2 * E_ + e];
            p1 = fmaf(v, w_g[e], p1);
        }
        p1 += __shfl_xor(p1, 1);
        p1 += __shfl_xor(p1, 2);
        p1 += __shfl_xor(p1, 4);
        if (k == 0) sc_l[r] = p1;
    }
    __syncthreads();

    const int qg = t & 31;
    const int cg = t >> 5;                   // 0..7
    const int c4 = cg * 4;
    const int q4 = qg * 4;

    // ---- phase 1: S[4c][4q] = scw3_tile @ xqT, 2-deep pipelined ----
    f32x4 acc[4] = {};
    const float* xqT_b = xqT_g + (size_t)b * E_ * Q_;
    f32x4 x0 = *(const f32x4*)&xqT_b[0 * Q_ + q4];
    f32x4 x1 = *(const f32x4*)&xqT_b[1 * Q_ + q4];
    f32x4 x2 = *(const f32x4*)&xqT_b[2 * Q_ + q4];
    f32x4 x3 = *(const f32x4*)&xqT_b[3 * Q_ + q4];
    for (int e = 0; e < E_ - 4; e += 4) {
        const f32x4 y0 = *(const f32x4*)&xqT_b[(e + 4) * Q_ + q4];
        const f32x4 y1 = *(const f32x4*)&xqT_b[(e + 5) * Q_ + q4];
        const f32x4 y2 = *(const f32x4*)&xqT_b[(e + 6) * Q_ + q4];
        const f32x4 y3 = *(const f32x4*)&xqT_b[(e + 7) * Q_ + q4];
        #pragma unroll
        for (int ci = 0; ci < 4; ++ci) {
            const f32x4 a = *(const f32x4*)&scw3_l[c4 + ci][e];  // broadcast: free
            acc[ci] += a.x * x0 + a.y * x1 + a.z * x2 + a.w * x3;
        }
        x0 = y0; x1 = y1; x2 = y2; x3 = y3;
    }
    #pragma unroll
    for (int ci = 0; ci < 4; ++ci) {         // e = 196
        const f32x4 a = *(const f32x4*)&scw3_l[c4 + ci][E_ - 4];
        acc[ci] += a.x * x0 + a.y * x1 + a.z * x2 + a.w * x3;
    }

    // ---- phase 2: in-register softmax over q (reduce across the 32-lane q-group) ----
    const f32x4 sqv = *(const f32x4*)&sq_g[b * Q_ + q4];
    float mx[4], sm[4];
    #pragma unroll
    for (int ci = 0; ci < 4; ++ci) {
        acc[ci] += sc_l[c4 + ci] + sqv;
        mx[ci] = fmaxf(fmaxf(acc[ci].x, acc[ci].y), fmaxf(acc[ci].z, acc[ci].w));
    }
    #pragma unroll
    for (int off = 16; off; off >>= 1) {
        #pragma unroll
        for (int ci = 0; ci < 4; ++ci) mx[ci] = fmaxf(mx[ci], __shfl_xor(mx[ci], off));
    }
    if (qg == 0) {
        #pragma unroll
        for (int ci = 0; ci < 4; ++ci) m_g[bc0 + c4 + ci] = mx[ci];
    }
    #pragma unroll
    for (int ci = 0; ci < 4; ++ci) {
        f32x4 p;
        p.x = __expf(acc[ci].x - mx[ci]);
        p.y = __expf(acc[ci].y - mx[ci]);
        p.z = __expf(acc[ci].z - mx[ci]);
        p.w = __expf(acc[ci].w - mx[ci]);
        acc[ci] = p;
        sm[ci] = (p.x + p.y) + (p.z + p.w);
    }
    #pragma unroll
    for (int off = 16; off; off >>= 1) {
        #pragma unroll
        for (int ci = 0; ci < 4; ++ci) sm[ci] += __shfl_xor(sm[ci], off);
    }
    #pragma unroll
    for (int ci = 0; ci < 4; ++ci) {
        acc[ci] *= (1.f / sm[ci]);
        *(f32x4*)&P_l[c4 + ci][q4] = acc[ci];   // normalized probs
    }

    // prefetch pass-0 q=0..3 BEFORE the barrier (xq_g independent of P_l)
    const float* xq_b = xq_g + (size_t)b * Q_ * E_;
    const int e4a = q4;                       // pass-0 column, < 128 always
    f32x4 v0 = *(const f32x4*)&xq_b[0 * E_ + e4a];
    f32x4 v1 = *(const f32x4*)&xq_b[1 * E_ + e4a];
    f32x4 v2 = *(const f32x4*)&xq_b[2 * E_ + e4a];
    f32x4 v3 = *(const f32x4*)&xq_b[3 * E_ + e4a];
    __syncthreads();

    // ---- phase 3 pass 0: c2q columns e4a, 2-deep pipelined ----
    {
        f32x4 o[4] = {};
        for (int q = 0; q < Q_ - 4; q += 4) {
            const f32x4 y0 = *(const f32x4*)&xq_b[(q + 4) * E_ + e4a];
            const f32x4 y1 = *(const f32x4*)&xq_b[(q + 5) * E_ + e4a];
            const f32x4 y2 = *(const f32x4*)&xq_b[(q + 6) * E_ + e4a];
            const f32x4 y3 = *(const f32x4*)&xq_b[(q + 7) * E_ + e4a];
            #pragma unroll
            for (int ci = 0; ci < 4; ++ci) {
                const f32x4 p = *(const f32x4*)&P_l[c4 + ci][q];  // broadcast
                o[ci] += p.x * v0 + p.y * v1 + p.z * v2 + p.w * v3;
            }
            v0 = y0; v1 = y1; v2 = y2; v3 = y3;
        }
        #pragma unroll
        for (int ci = 0; ci < 4; ++ci) {      // q = 124
            const f32x4 p = *(const f32x4*)&P_l[c4 + ci][Q_ - 4];
            o[ci] += p.x * v0 + p.y * v1 + p.z * v2 + p.w * v3;
        }
        #pragma unroll
        for (int ci = 0; ci < 4; ++ci) {
            const size_t row = (size_t)(bc0 + c4 + ci);
            const f32x4 xcv = *(const f32x4*)&xc_g[row * E_ + e4a];
            float* orow = out + row * (4 * E_);
            *(f32x4*)&orow[e4a]          = xcv;
            *(f32x4*)&orow[E_ + e4a]     = o[ci];
            *(f32x4*)&orow[2 * E_ + e4a] = xcv * o[ci];
        }
    }

    // ---- phase 3 pass 1: columns e4b = 128 + q4 (active when < 200) ----
    const int e4b = 128 + q4;
    if (e4b < E_) {
        f32x4 w0 = *(const f32x4*)&xq_b[0 * E_ + e4b];
        f32x4 w1 = *(const f32x4*)&xq_b[1 * E_ + e4b];
        f32x4 w2 = *(const f32x4*)&xq_b[2 * E_ + e4b];
        f32x4 w3 = *(const f32x4*)&xq_b[3 * E_ + e4b];
        f32x4 o[4] = {};
        for (int q = 0; q < Q_ - 4; q += 4) {
            const f32x4 y0 = *(const f32x4*)&xq_b[(q + 4) * E_ + e4b];
            const f32x4 y1 = *(const f32x4*)&xq_b[(q + 5) * E_ + e4b];
            const f32x4 y2 = *(const f32x4*)&xq_b[(q + 6) * E_ + e4b];
            const f32x4 y3 = *(const f32x4*)&xq_b[(q + 7) * E_ + e4b];
            #pragma unroll
            for (int ci = 0; ci < 4; ++ci) {
                const f32x4 p = *(const f32x4*)&P_l[c4 + ci][q];  // broadcast
                o[ci] += p.x * w0 + p.y * w1 + p.z * w2 + p.w * w3;
            }
            w0 = y0; w1 = y1; w2 = y2; w3 = y3;
        }
        #pragma unroll
        for (int ci = 0; ci < 4; ++ci) {      // q = 124
            const f32x4 p = *(const f32x4*)&P_l[c4 + ci][Q_ - 4];
            o[ci] += p.x * w0 + p.y * w1 + p.z * w2 + p.w * w3;
        }
        #pragma unroll
        for (int ci = 0; ci < 4; ++ci) {
            const size_t row = (size_t)(bc0 + c4 + ci);
            const f32x4 xcv = *(const f32x4*)&xc_g[row * E_ + e4b];
            float* orow = out + row * (4 * E_);
            *(f32x4*)&orow[e4b]          = xcv;
            *(f32x4*)&orow[E_ + e4b]     = o[ci];
            *(f32x4*)&orow[2 * E_ + e4b] = xcv * o[ci];
        }
    }
}

// ---------------------------------------------------------------- K3
// Fused stats + partial q2c. Each block: global per-b max M over m[b,:]
// (redundant, bitwise-identical across blocks), then its 64-c chunk:
//   part[blk][e] = sum_c exp(m[c]-M)*xc[c][e];  den[blk] = sum_c exp(m[c]-M)
__global__ __launch_bounds__(256) void q2c_partial(const float* __restrict__ xc_g,
                                                   const float* __restrict__ m_g,
                                                   float* __restrict__ part,
                                                   float* __restrict__ den) {
    __shared__ float redl[4];
    __shared__ float wl[64];
    const int blk = blockIdx.x;               // 0..B*32-1
    const int b = blk >> 5, g = blk & 31;     // 32 chunks of 64 c per b
    const int t = threadIdx.x;
    const int c0 = g * 64;

    // global max over m[b, 0:2048]
    float mx = -3.4e38f;
    #pragma unroll
    for (int j = 0; j < 8; ++j) mx = fmaxf(mx, m_g[b * C_ + t + j * 256]);
    #pragma unroll
    for (int off = 32; off; off >>= 1) mx = fmaxf(mx, __shfl_xor(mx, off));
    if ((t & 63) == 0) redl[t >> 6] = mx;
    __syncthreads();
    const float M = fmaxf(fmaxf(redl[0], redl[1]), fmaxf(redl[2], redl[3]));

    if (t < 64) {                              // wave 0: chunk weights
        const float e = __expf(m_g[b * C_ + c0 + t] - M);
        wl[t] = e;
        float s = e;
        #pragma unroll
        for (int off = 32; off; off >>= 1) s += __shfl_xor(s, off);
        if (t == 0) den[blk] = s;
    }
    __syncthreads();

    if (t < E_) {
        float acc = 0.f;
        const float* base = xc_g + ((size_t)(b * C_ + c0)) * E_ + t;
        #pragma unroll 8
        for (int c = 0; c < 64; ++c) acc = fmaf(wl[c], base[(size_t)c * E_], acc);
        part[(size_t)blk * E_ + t] = acc;
    }
}

// ---------------------------------------------------------------- K4
// Fused reduce + segment-3 write. Block = 64 c-rows of one b:
//   q2c[e] = (sum_g part[g][e]) / (sum_g den[g]);  out[...,3E:4E] = xc * q2c
__global__ __launch_bounds__(256) void out4_kernel(const float* __restrict__ xc_g,
                                                   const float* __restrict__ part,
                                                   const float* __restrict__ den,
                                                   float* __restrict__ out) {
    __shared__ float q2c_l[E_];
    __shared__ float invt;
    const int blk = blockIdx.x;               // 0..B*32-1
    const int b = blk >> 5, g = blk & 31;
    const int c0 = g * 64;
    const int t = threadIdx.x;

    if (t < E_) {
        float a = 0.f;
        #pragma unroll
        for (int gg = 0; gg < 32; ++gg) a += part[(size_t)(b * 32 + gg) * E_ + t];
        q2c_l[t] = a;
    }
    if (t >= 224) {                            // lanes 32..63 of wave 3
        float s = den[b * 32 + (t - 224)];
        #pragma unroll
        for (int off = 16; off; off >>= 1) s += __shfl_xor(s, off);
        if (t == 224) invt = 1.f / s;
    }
    __syncthreads();

    const float iv = invt;
    const int e4 = (t % 50) * 4;
    const int r0 = t / 50;                     // 0..3 (t<200), t>=200 idle
    if (t < 200) {
        #pragma unroll
        for (int kk = 0; kk < 16; ++kk) {
            const size_t row = (size_t)(b * C_ + c0 + kk * 4 + r0);
            const f32x4 xcv = *(const f32x4*)&xc_g[row * E_ + e4];
            const f32x4 qv  = *(const f32x4*)&q2c_l[e4];
            *(f32x4*)&out[row * (4 * E_) + 3 * E_ + e4] = xcv * (qv * iv);
        }
    }
}

extern "C" void kernel_launch(void* const* d_in, const int* in_sizes, int n_in,
                              void* d_out, int out_size, void* d_ws, size_t ws_size,
                              hipStream_t stream) {
    // order-robust input selection by element count
    const float* xc = (const float*)d_in[0];
    const float* xq = (const float*)d_in[1];
    const float* w  = (const float*)d_in[2];
    for (int i = 0; i < n_in; ++i) {
        if      (in_sizes[i] == B_ * C_ * E_) xc = (const float*)d_in[i];
        else if (in_sizes[i] == B_ * Q_ * E_) xq = (const float*)d_in[i];
        else if (in_sizes[i] == 3 * E_)       w  = (const float*)d_in[i];
    }
    float* out = (float*)d_out;

    float* ws    = (float*)d_ws;
    float* sq    = ws;                 // B*Q   = 4096
    float* m     = sq + B_ * Q_;       // B*C   = 65536
    float* xqT   = m + B_ * C_;        // B*E*Q = 819200  (~3.3 MB)
    // part/den alias xqT: written only AFTER row2's last xqT read (stream-ordered);
    // 1024*200 + 1024 = 205824 floats fits well inside xqT's 819200.
    float* part  = xqT;                            // [B*32][E_]
    float* den   = xqT + 1024 * E_;                // [B*32]

    prep_kernel <<<1920,               256, 0, stream>>>(xq, w, xqT, sq);
    row2_kernel <<<B_ * (C_ / TB),     256, 0, stream>>>(xc, xq, xqT, w, sq, m, out);
    q2c_partial <<<B_ * 32,            256, 0, stream>>>(xc, m, part, den);
    out4_kernel <<<B_ * 32,            256, 0, stream>>>(xc, part, den, out);
}